// Round 7
// baseline (4971.635 us; speedup 1.0000x reference)
//
#include <hip/hip_runtime.h>

#define D 256          // D_IN == D_OUT == 256
#define BSHIFT 6       // 64 rows per bucket
#define BROWS 64
#define CHUNK 8192     // edges per bucket_hist / bucket_scatter block
// NB = ceil(N/64) = 1563 for N=100000; kernels assume NB <= 2048

typedef __attribute__((ext_vector_type(8))) short bf16x8;  // 8 bf16 in 4 VGPRs
typedef __attribute__((ext_vector_type(4))) float f32x4;

__device__ inline ushort f2bf_rne(float f) {  // fp32 -> bf16, round-to-nearest-even
    uint u = __builtin_bit_cast(uint, f);
    return (ushort)((u + 0x7FFFu + ((u >> 16) & 1u)) >> 16);
}

// ===========================================================================
// W transpose + bf16 convert: wt[n][k] = bf16(W[k][n])
// ===========================================================================
__global__ __launch_bounds__(256) void conv_wt(const float* __restrict__ w,
                                               ushort* __restrict__ wt) {
    const int idx = blockIdx.x * 256 + threadIdx.x;
    const int n = idx >> 8, k = idx & 255;
    wt[n * 256 + k] = f2bf_rne(w[k * 256 + n]);
}

// ===========================================================================
// support = bf16(x @ W) via MFMA 16x16x32 bf16.  (unchanged — verified)
// ===========================================================================
__global__ __launch_bounds__(256) void gemm_mfma(const float* __restrict__ x,
                                                 const ushort* __restrict__ wt,
                                                 ushort* __restrict__ sup,
                                                 int N) {
    __shared__ ushort As[64 * 256];  // 32 KB, XOR-swizzled
    const int tid = threadIdx.x;
    const int wv  = tid >> 6;
    const int ln  = tid & 63;
    const int row0 = blockIdx.x * 64;

    for (int i = tid; i < 64 * 64; i += 256) {
        const int r = i >> 6, c = i & 63;
        int gr = row0 + r;
        if (gr >= N) gr = N - 1;
        const float4 xv = *(const float4*)(x + (size_t)gr * D + c * 4);
        ushort4 b;
        b.x = f2bf_rne(xv.x); b.y = f2bf_rne(xv.y);
        b.z = f2bf_rne(xv.z); b.w = f2bf_rne(xv.w);
        const int byte = (r * 512 + c * 8) ^ ((r & 7) << 4);
        *(ushort4*)((char*)As + byte) = b;
    }
    __syncthreads();

    f32x4 acc[16];
#pragma unroll
    for (int n = 0; n < 16; ++n) acc[n] = (f32x4){0.f, 0.f, 0.f, 0.f};

    const int arow = wv * 16 + (ln & 15);
    const int ksub = (ln >> 4) * 16;
    const ushort* wbase = wt + (ln & 15) * 256;

#pragma unroll
    for (int kk = 0; kk < 8; ++kk) {
        const int abyte = (arow * 512 + kk * 64 + ksub) ^ ((arow & 7) << 4);
        const bf16x8 af = *(const bf16x8*)((const char*)As + abyte);
        const ushort* wp = wbase + kk * 32 + (ln >> 4) * 8;
#pragma unroll
        for (int n = 0; n < 16; ++n) {
            const bf16x8 bf = *(const bf16x8*)(wp + n * 16 * 256);
            acc[n] = __builtin_amdgcn_mfma_f32_16x16x32_bf16(af, bf, acc[n], 0, 0, 0);
        }
    }

    const int crow = row0 + wv * 16 + (ln >> 4) * 4;
    const int ccol = ln & 15;
#pragma unroll
    for (int n = 0; n < 16; ++n) {
#pragma unroll
        for (int reg = 0; reg < 4; ++reg) {
            const int r = crow + reg;
            if (r < N) sup[(size_t)r * D + n * 16 + ccol] = f2bf_rne(acc[n][reg]);
        }
    }
}

// ===========================================================================
// zero helper
// ===========================================================================
__global__ __launch_bounds__(256) void zero_ints(int* __restrict__ p, int n) {
    const int i = blockIdx.x * 256 + threadIdx.x;
    if (i < n) p[i] = 0;
}

// ===========================================================================
// Bucket-level histogram: LDS hist per CHUNK, one global atomic per
// (block,bucket).  ~611K global atomics vs 3.2M for the old per-row hist.
// ===========================================================================
__global__ __launch_bounds__(256) void bucket_hist(const int* __restrict__ edge_row,
                                                   int* __restrict__ bcnt,
                                                   int E, int NB) {
    __shared__ int bh[2048];
    const int tid = threadIdx.x;
    for (int i = tid; i < 2048; i += 256) bh[i] = 0;
    __syncthreads();

    const int e0 = blockIdx.x * CHUNK;
    const int e1 = min(e0 + CHUNK, E);
    for (int i = e0 + tid * 4; i < e1; i += 1024) {
        if (i + 3 < e1) {
            const int4 r = *(const int4*)(edge_row + i);
            atomicAdd(&bh[r.x >> BSHIFT], 1);
            atomicAdd(&bh[r.y >> BSHIFT], 1);
            atomicAdd(&bh[r.z >> BSHIFT], 1);
            atomicAdd(&bh[r.w >> BSHIFT], 1);
        } else {
            for (int j = i; j < e1; ++j) atomicAdd(&bh[edge_row[j] >> BSHIFT], 1);
        }
    }
    __syncthreads();

    for (int b = tid; b < NB; b += 256) {
        const int c = bh[b];
        if (c) atomicAdd(&bcnt[b], c);
    }
}

// ===========================================================================
// Single-block exclusive scan over NB <= 2048 bucket counts.
// Writes bstart (prefix), bcursor (mutable copy), bstart[NB] = E.
// ===========================================================================
__global__ __launch_bounds__(512) void bucket_scan(const int* __restrict__ bcnt,
                                                   int* __restrict__ bstart,
                                                   int* __restrict__ bcursor,
                                                   int NB, int E) {
    __shared__ int psum[512];
    const int tid = threadIdx.x;
    int v[4];
    int s = 0;
#pragma unroll
    for (int k = 0; k < 4; ++k) {
        const int i = tid * 4 + k;
        v[k] = (i < NB) ? bcnt[i] : 0;
        s += v[k];
    }
    psum[tid] = s;
    __syncthreads();
#pragma unroll
    for (int off = 1; off < 512; off <<= 1) {
        const int t = (tid >= off) ? psum[tid - off] : 0;
        __syncthreads();
        psum[tid] += t;
        __syncthreads();
    }
    int run = psum[tid] - s;  // exclusive prefix of this thread's 4-group
#pragma unroll
    for (int k = 0; k < 4; ++k) {
        const int i = tid * 4 + k;
        if (i < NB) { bstart[i] = run; bcursor[i] = run; }
        run += v[k];
    }
    if (tid == 0) bstart[NB] = E;
}

// ===========================================================================
// Bucket scatter (pass A of round 5, BROWS=64): LDS hist -> one global atomic
// per (block,bucket) reserves a run -> edges written via LDS cursors.
// Entry: val_bf16(16) << 48 | col(17) << 17 | row(17).
// ===========================================================================
__global__ __launch_bounds__(256) void bucket_scatter(
        const int* __restrict__ edge_row, const int* __restrict__ edge_col,
        const float* __restrict__ edge_val, int* __restrict__ bucket_cursor,
        unsigned long long* __restrict__ ebuck, int E, int NB) {
    __shared__ int cur[2048];
    const int tid = threadIdx.x;
    const int e0  = blockIdx.x * CHUNK;
    const int e1  = min(e0 + CHUNK, E);

    for (int i = tid; i < 2048; i += 256) cur[i] = 0;
    __syncthreads();

    for (int e = e0 + tid; e < e1; e += 256)
        atomicAdd(&cur[edge_row[e] >> BSHIFT], 1);
    __syncthreads();

    for (int b = tid; b < NB; b += 256) {
        const int c = cur[b];
        cur[b] = (c > 0) ? atomicAdd(&bucket_cursor[b], c) : 0;
    }
    __syncthreads();

    for (int e = e0 + tid; e < e1; e += 256) {
        const int r = edge_row[e];
        const int b = r >> BSHIFT;
        const int pos = atomicAdd(&cur[b], 1);
        const unsigned long long pk =
            ((unsigned long long)(uint)f2bf_rne(edge_val[e]) << 48) |
            ((unsigned long long)(uint)edge_col[e] << 17) | (uint)r;
        ebuck[pos] = pk;
    }
}

// ===========================================================================
// Bucket accumulate: one block per 64-row bucket, 64x256 fp32 tile in LDS
// (64 KB -> 2 blocks/CU).  Consumes bucket-sorted ebuck directly — no fine
// sort, no row_start, no epair.  Lane l owns dims {l, l+64, l+128, l+192}:
// ds_add_f32 is lane-stride-1 -> 2-way bank access = free (lane-consecutive
// ownership would be 8-way and serialize the LDS pipe).  Gathers: 4 x 128 B
// coalesced ushort loads per edge (same line footprint as one 512 B read),
// 8 edges in flight per wave.
// ===========================================================================
__global__ __launch_bounds__(256) void bucket_accumulate(
        const ushort* __restrict__ sup,
        const unsigned long long* __restrict__ ebuck,
        const int* __restrict__ bstart,
        const float* __restrict__ bias,
        float* __restrict__ out, int N) {
    __shared__ float acc[BROWS * 256];  // 64 KB
    const int tid  = threadIdx.x;
    const int lane = tid & 63;
    const int r0   = blockIdx.x << BSHIFT;

    for (int i = tid; i < BROWS * 64; i += 256)
        *(f32x4*)(acc + i * 4) = (f32x4){0.f, 0.f, 0.f, 0.f};
    __syncthreads();

    const int s = bstart[blockIdx.x];
    const int e = bstart[blockIdx.x + 1];

    for (int base = s + (tid >> 6) * 64; base < e; base += 256) {
        const int idx = base + lane;
        unsigned long long pk = 0;
        if (idx < e) pk = ebuck[idx];
        const int   er = (int)(pk & 0x1FFFFu) - r0;  // 0..63 for active lanes
        const int   ec = (int)((pk >> 17) & 0x1FFFFu);
        const float ev = __builtin_bit_cast(float, (uint)(pk >> 48) << 16);
        const int n = min(64, e - base);
        int j = 0;
        for (; j + 7 < n; j += 8) {
            int rq[8], cq[8];
            float vq[8];
            uint uq[8][4];
#pragma unroll
            for (int q = 0; q < 8; ++q) {
                rq[q] = __shfl(er, j + q);
                cq[q] = __shfl(ec, j + q);
                vq[q] = __shfl(ev, j + q);
            }
#pragma unroll
            for (int q = 0; q < 8; ++q) {
                const ushort* sp = sup + ((uint)cq[q] << 8) + lane;
                uq[q][0] = sp[0];
                uq[q][1] = sp[64];
                uq[q][2] = sp[128];
                uq[q][3] = sp[192];
            }
#pragma unroll
            for (int q = 0; q < 8; ++q) {
                float* ap = acc + rq[q] * 256 + lane;
                atomicAdd(ap,       vq[q] * __builtin_bit_cast(float, uq[q][0] << 16));
                atomicAdd(ap + 64,  vq[q] * __builtin_bit_cast(float, uq[q][1] << 16));
                atomicAdd(ap + 128, vq[q] * __builtin_bit_cast(float, uq[q][2] << 16));
                atomicAdd(ap + 192, vq[q] * __builtin_bit_cast(float, uq[q][3] << 16));
            }
        }
        for (; j < n; ++j) {
            const int   r1 = __shfl(er, j);
            const int   c1 = __shfl(ec, j);
            const float v1 = __shfl(ev, j);
            const ushort* sp = sup + ((uint)c1 << 8) + lane;
            const uint u0 = sp[0], u1 = sp[64], u2 = sp[128], u3 = sp[192];
            float* ap = acc + r1 * 256 + lane;
            atomicAdd(ap,       v1 * __builtin_bit_cast(float, u0 << 16));
            atomicAdd(ap + 64,  v1 * __builtin_bit_cast(float, u1 << 16));
            atomicAdd(ap + 128, v1 * __builtin_bit_cast(float, u2 << 16));
            atomicAdd(ap + 192, v1 * __builtin_bit_cast(float, u3 << 16));
        }
    }
    __syncthreads();

    // write out + bias (rows with no edges correctly get pure bias)
    for (int i = tid; i < BROWS * 64; i += 256) {
        const int r  = i >> 6;
        const int c4 = i & 63;
        const int row = r0 + r;
        if (row < N) {
            f32x4 a = *(const f32x4*)(acc + r * 256 + c4 * 4);
            const f32x4 b = *(const f32x4*)(bias + c4 * 4);
            a[0] += b[0]; a[1] += b[1]; a[2] += b[2]; a[3] += b[3];
            __builtin_nontemporal_store(a, (f32x4*)(out + (size_t)row * D + c4 * 4));
        }
    }
}

// ===========================================================================
extern "C" void kernel_launch(void* const* d_in, const int* in_sizes, int n_in,
                              void* d_out, int out_size, void* d_ws, size_t ws_size,
                              hipStream_t stream) {
    const float* x        = (const float*)d_in[0];
    const float* edge_val = (const float*)d_in[1];
    const float* weight   = (const float*)d_in[2];
    const float* bias     = (const float*)d_in[3];
    const int*   edge_row = (const int*)d_in[4];
    const int*   edge_col = (const int*)d_in[5];
    float*       out      = (float*)d_out;

    const int N = in_sizes[0] / D;   // 100000
    const int E = in_sizes[1];       // 3200000

    char* ws = (char*)d_ws;
    size_t off = 0;
    auto carve = [&](size_t bytes) -> char* {
        char* p = ws + off;
        off = (off + bytes + 255) & ~(size_t)255;
        return p;
    };

    const int NB = (N + BROWS - 1) / BROWS;  // 1563 buckets

    ushort* sup = (ushort*)carve((size_t)N * D * sizeof(ushort));   // 51.2 MB
    ushort* wt  = (ushort*)carve((size_t)D * D * sizeof(ushort));   // 128 KB
    unsigned long long* ebuck =
        (unsigned long long*)carve((size_t)E * sizeof(unsigned long long));  // 25.6 MB
    int* bcnt    = (int*)carve((size_t)NB * sizeof(int));
    int* bstart  = (int*)carve((size_t)(NB + 1) * sizeof(int));
    int* bcursor = (int*)carve((size_t)NB * sizeof(int));

    const int nchunk = (E + CHUNK - 1) / CHUNK;  // 391

    // 1) W -> wt (bf16 transposed), support = bf16(x @ W)
    conv_wt<<<(D * D) / 256, 256, 0, stream>>>(weight, wt);
    gemm_mfma<<<(N + 63) / 64, 256, 0, stream>>>(x, wt, sup, N);

    // 2) bucket hist + scan + scatter (row-sort only to 64-row granularity)
    zero_ints<<<(NB + 255) / 256, 256, 0, stream>>>(bcnt, NB);
    bucket_hist<<<nchunk, 256, 0, stream>>>(edge_row, bcnt, E, NB);
    bucket_scan<<<1, 512, 0, stream>>>(bcnt, bstart, bcursor, NB, E);
    bucket_scatter<<<nchunk, 256, 0, stream>>>(edge_row, edge_col, edge_val,
                                               bcursor, ebuck, E, NB);

    // 3) per-bucket LDS-tile accumulate (bias folded in)
    bucket_accumulate<<<NB, 256, 0, stream>>>(sup, ebuck, bstart, bias, out, N);
}

// Round 8
// 448.144 us; speedup vs baseline: 11.0938x; 11.0938x over previous
//
#include <hip/hip_runtime.h>

#define D 256          // D_IN == D_OUT == 256
#define BSHIFT 7       // 128 rows per coarse bucket
#define BROWS 128
#define CHUNK 8192     // edges per bucket_hist / bucket_scatter block
// NB = ceil(100000/128) = 782; kernels assume NB <= 1024 (hist) / 2048 (scan)

typedef __attribute__((ext_vector_type(8))) short bf16x8;  // 8 bf16 in 4 VGPRs
typedef __attribute__((ext_vector_type(4))) float f32x4;

__device__ inline ushort f2bf_rne(float f) {  // fp32 -> bf16, round-to-nearest-even
    uint u = __builtin_bit_cast(uint, f);
    return (ushort)((u + 0x7FFFu + ((u >> 16) & 1u)) >> 16);
}

// ===========================================================================
// W transpose + bf16 convert: wt[n][k] = bf16(W[k][n])
// ===========================================================================
__global__ __launch_bounds__(256) void conv_wt(const float* __restrict__ w,
                                               ushort* __restrict__ wt) {
    const int idx = blockIdx.x * 256 + threadIdx.x;
    const int n = idx >> 8, k = idx & 255;
    wt[n * 256 + k] = f2bf_rne(w[k * 256 + n]);
}

// ===========================================================================
// support = bf16(x @ W) via MFMA 16x16x32 bf16.  (verified rounds 3-6)
// ===========================================================================
__global__ __launch_bounds__(256) void gemm_mfma(const float* __restrict__ x,
                                                 const ushort* __restrict__ wt,
                                                 ushort* __restrict__ sup,
                                                 int N) {
    __shared__ ushort As[64 * 256];  // 32 KB, XOR-swizzled
    const int tid = threadIdx.x;
    const int wv  = tid >> 6;
    const int ln  = tid & 63;
    const int row0 = blockIdx.x * 64;

    for (int i = tid; i < 64 * 64; i += 256) {
        const int r = i >> 6, c = i & 63;
        int gr = row0 + r;
        if (gr >= N) gr = N - 1;
        const float4 xv = *(const float4*)(x + (size_t)gr * D + c * 4);
        ushort4 b;
        b.x = f2bf_rne(xv.x); b.y = f2bf_rne(xv.y);
        b.z = f2bf_rne(xv.z); b.w = f2bf_rne(xv.w);
        const int byte = (r * 512 + c * 8) ^ ((r & 7) << 4);
        *(ushort4*)((char*)As + byte) = b;
    }
    __syncthreads();

    f32x4 acc[16];
#pragma unroll
    for (int n = 0; n < 16; ++n) acc[n] = (f32x4){0.f, 0.f, 0.f, 0.f};

    const int arow = wv * 16 + (ln & 15);
    const int ksub = (ln >> 4) * 16;
    const ushort* wbase = wt + (ln & 15) * 256;

#pragma unroll
    for (int kk = 0; kk < 8; ++kk) {
        const int abyte = (arow * 512 + kk * 64 + ksub) ^ ((arow & 7) << 4);
        const bf16x8 af = *(const bf16x8*)((const char*)As + abyte);
        const ushort* wp = wbase + kk * 32 + (ln >> 4) * 8;
#pragma unroll
        for (int n = 0; n < 16; ++n) {
            const bf16x8 bf = *(const bf16x8*)(wp + n * 16 * 256);
            acc[n] = __builtin_amdgcn_mfma_f32_16x16x32_bf16(af, bf, acc[n], 0, 0, 0);
        }
    }

    const int crow = row0 + wv * 16 + (ln >> 4) * 4;
    const int ccol = ln & 15;
#pragma unroll
    for (int n = 0; n < 16; ++n) {
#pragma unroll
        for (int reg = 0; reg < 4; ++reg) {
            const int r = crow + reg;
            if (r < N) sup[(size_t)r * D + n * 16 + ccol] = f2bf_rne(acc[n][reg]);
        }
    }
}

// ===========================================================================
__global__ __launch_bounds__(256) void zero_ints(int* __restrict__ p, int n) {
    const int i = blockIdx.x * 256 + threadIdx.x;
    if (i < n) p[i] = 0;
}

// ===========================================================================
// Bucket-level histogram: LDS hist per CHUNK, <= NB global atomics per block
// (~306K total vs 3.2M for the old per-row hist).
// ===========================================================================
__global__ __launch_bounds__(256) void bucket_hist(const int* __restrict__ edge_row,
                                                   int* __restrict__ bcnt,
                                                   int E, int NB) {
    __shared__ int bh[1024];
    const int tid = threadIdx.x;
    for (int i = tid; i < 1024; i += 256) bh[i] = 0;
    __syncthreads();

    const int e0 = blockIdx.x * CHUNK;
    const int e1 = min(e0 + CHUNK, E);
    for (int i = e0 + tid * 4; i < e1; i += 1024) {
        if (i + 3 < e1) {
            const int4 r = *(const int4*)(edge_row + i);
            atomicAdd(&bh[r.x >> BSHIFT], 1);
            atomicAdd(&bh[r.y >> BSHIFT], 1);
            atomicAdd(&bh[r.z >> BSHIFT], 1);
            atomicAdd(&bh[r.w >> BSHIFT], 1);
        } else {
            for (int j = i; j < e1; ++j) atomicAdd(&bh[edge_row[j] >> BSHIFT], 1);
        }
    }
    __syncthreads();

    for (int b = tid; b < NB; b += 256) {
        const int c = bh[b];
        if (c) atomicAdd(&bcnt[b], c);
    }
}

// ===========================================================================
// Single-block exclusive scan over NB <= 2048 bucket counts.
// bstart (prefix), bcursor (mutable copy), bstart[NB] = E, row_start[N] = E.
// ===========================================================================
__global__ __launch_bounds__(512) void bucket_scan(const int* __restrict__ bcnt,
                                                   int* __restrict__ bstart,
                                                   int* __restrict__ bcursor,
                                                   int* __restrict__ row_start,
                                                   int NB, int N, int E) {
    __shared__ int psum[512];
    const int tid = threadIdx.x;
    int v[4];
    int s = 0;
#pragma unroll
    for (int k = 0; k < 4; ++k) {
        const int i = tid * 4 + k;
        v[k] = (i < NB) ? bcnt[i] : 0;
        s += v[k];
    }
    psum[tid] = s;
    __syncthreads();
#pragma unroll
    for (int off = 1; off < 512; off <<= 1) {
        const int t = (tid >= off) ? psum[tid - off] : 0;
        __syncthreads();
        psum[tid] += t;
        __syncthreads();
    }
    int run = psum[tid] - s;  // exclusive prefix of this thread's 4-group
#pragma unroll
    for (int k = 0; k < 4; ++k) {
        const int i = tid * 4 + k;
        if (i < NB) { bstart[i] = run; bcursor[i] = run; }
        run += v[k];
    }
    if (tid == 0) { bstart[NB] = E; row_start[N] = E; }
}

// ===========================================================================
// Pass A: coarse bucket scatter (proven round 5).  LDS hist -> one global
// atomic per (block,bucket) reserves a run -> edges written via LDS cursors.
// Entry: val_bf16(16) << 48 | col(17) << 17 | row(17).
// ===========================================================================
__global__ __launch_bounds__(256) void bucket_scatter(
        const int* __restrict__ edge_row, const int* __restrict__ edge_col,
        const float* __restrict__ edge_val, int* __restrict__ bucket_cursor,
        unsigned long long* __restrict__ ebuck, int E, int NB) {
    __shared__ int cur[1024];
    const int tid = threadIdx.x;
    const int e0  = blockIdx.x * CHUNK;
    const int e1  = min(e0 + CHUNK, E);

    for (int i = tid; i < 1024; i += 256) cur[i] = 0;
    __syncthreads();

    for (int e = e0 + tid; e < e1; e += 256)
        atomicAdd(&cur[edge_row[e] >> BSHIFT], 1);
    __syncthreads();

    for (int b = tid; b < NB; b += 256) {
        const int c = cur[b];
        cur[b] = (c > 0) ? atomicAdd(&bucket_cursor[b], c) : 0;
    }
    __syncthreads();

    for (int e = e0 + tid; e < e1; e += 256) {
        const int r = edge_row[e];
        const int b = r >> BSHIFT;
        const int pos = atomicAdd(&cur[b], 1);
        const unsigned long long pk =
            ((unsigned long long)(uint)f2bf_rne(edge_val[e]) << 48) |
            ((unsigned long long)(uint)edge_col[e] << 17) | (uint)r;
        ebuck[pos] = pk;
    }
}

// packed (col, val): low 32 = col, high 32 = val bits
__device__ inline long long pack_cv(int c, float v) {
    return (long long)(((unsigned long long)__builtin_bit_cast(uint, v) << 32) |
                       (uint)c);
}

// ===========================================================================
// Pass B: fine scatter, row_start fused.  Block b owns bucket b:
// count its 128 rows in LDS -> block scan -> write row_start -> scatter.
// epair target window ~32KB => L2-resident full-line writebacks.
// ===========================================================================
__global__ __launch_bounds__(256) void fine_scatter(
        const unsigned long long* __restrict__ ebuck,
        const int* __restrict__ bstart,
        long long* __restrict__ epair,
        int* __restrict__ row_start, int N) {
    __shared__ int cnt[BROWS];
    __shared__ int cur[BROWS];
    const int tid = threadIdx.x;
    const int r0  = blockIdx.x << BSHIFT;
    const int s   = bstart[blockIdx.x];
    const int e   = bstart[blockIdx.x + 1];

    if (tid < BROWS) cnt[tid] = 0;
    __syncthreads();

    // pass 1: per-row count
    for (int i = s + tid; i < e; i += 256)
        atomicAdd(&cnt[(int)(ebuck[i] & 0x1FFFFu) - r0], 1);
    __syncthreads();

    // block scan of 128 counters (Hillis-Steele in cur)
    if (tid < BROWS) cur[tid] = cnt[tid];
    __syncthreads();
#pragma unroll
    for (int off = 1; off < BROWS; off <<= 1) {
        const int t = (tid < BROWS && tid >= off) ? cur[tid - off] : 0;
        __syncthreads();
        if (tid < BROWS) cur[tid] += t;
        __syncthreads();
    }
    if (tid < BROWS) {
        const int rs = s + cur[tid] - cnt[tid];  // exclusive
        cur[tid] = rs;                           // becomes cursor
        const int row = r0 + tid;
        if (row < N) row_start[row] = rs;
    }
    __syncthreads();

    // pass 2: scatter into the row-sorted segment
    for (int i = s + tid; i < e; i += 256) {
        const unsigned long long pk = ebuck[i];
        const int  r  = (int)(pk & 0x1FFFFu) - r0;
        const int  c  = (int)((pk >> 17) & 0x1FFFFu);
        const float v = __builtin_bit_cast(float, (uint)(pk >> 48) << 16);
        const int pos = atomicAdd(&cur[r], 1);
        epair[pos] = pack_cv(c, v);
    }
}

// ===========================================================================
// accumulate: one wave per row; 8 gathers in flight; bias folded in.
// (byte-identical to rounds 4-6 — proven, 223 µs)
// ===========================================================================
__global__ __launch_bounds__(256) void accumulate(const ushort* __restrict__ sup,
                                                  const int* __restrict__ row_start,
                                                  const long long* __restrict__ epair,
                                                  const float* __restrict__ bias,
                                                  float* __restrict__ out, int N) {
    const int row = blockIdx.x * 4 + (threadIdx.x >> 6);
    if (row >= N) return;
    const int lane = threadIdx.x & 63;
    const int lofs = lane * 4;  // ushort offset within a sup row

    const int s = row_start[row];
    const int e = row_start[row + 1];

    f32x4 a[8];
    a[0] = *(const f32x4*)(bias + lofs);
#pragma unroll
    for (int q = 1; q < 8; ++q) a[q] = (f32x4){0.f, 0.f, 0.f, 0.f};

    for (int base = s; base < e; base += 64) {
        const int idx = base + lane;
        long long pk = 0;
        if (idx < e) pk = __builtin_nontemporal_load(epair + idx);
        const int   c = (int)(uint)pk;
        const float v = __builtin_bit_cast(float, (uint)((unsigned long long)pk >> 32));
        const int n = min(64, e - base);
        int j = 0;
        for (; j + 7 < n; j += 8) {
            int   cq[8];
            float vq[8];
            uint2 uq[8];
#pragma unroll
            for (int q = 0; q < 8; ++q) {
                cq[q] = __shfl(c, j + q);
                vq[q] = __shfl(v, j + q);
            }
#pragma unroll
            for (int q = 0; q < 8; ++q)
                uq[q] = *(const uint2*)(sup + ((uint)cq[q] << 8) + lofs);
#pragma unroll
            for (int q = 0; q < 8; ++q) {
                const float f0 = __builtin_bit_cast(float, uq[q].x << 16);
                const float f1 = __builtin_bit_cast(float, uq[q].x & 0xFFFF0000u);
                const float f2 = __builtin_bit_cast(float, uq[q].y << 16);
                const float f3 = __builtin_bit_cast(float, uq[q].y & 0xFFFF0000u);
                a[q][0] = fmaf(vq[q], f0, a[q][0]);
                a[q][1] = fmaf(vq[q], f1, a[q][1]);
                a[q][2] = fmaf(vq[q], f2, a[q][2]);
                a[q][3] = fmaf(vq[q], f3, a[q][3]);
            }
        }
        for (; j < n; ++j) {
            const int   c0 = __shfl(c, j);
            const float v0 = __shfl(v, j);
            const uint2 u  = *(const uint2*)(sup + ((uint)c0 << 8) + lofs);
            const float f0 = __builtin_bit_cast(float, u.x << 16);
            const float f1 = __builtin_bit_cast(float, u.x & 0xFFFF0000u);
            const float f2 = __builtin_bit_cast(float, u.y << 16);
            const float f3 = __builtin_bit_cast(float, u.y & 0xFFFF0000u);
            a[0][0] = fmaf(v0, f0, a[0][0]);
            a[0][1] = fmaf(v0, f1, a[0][1]);
            a[0][2] = fmaf(v0, f2, a[0][2]);
            a[0][3] = fmaf(v0, f3, a[0][3]);
        }
    }
#pragma unroll
    for (int q = 1; q < 8; ++q) {
        a[0][0] += a[q][0]; a[0][1] += a[q][1];
        a[0][2] += a[q][2]; a[0][3] += a[q][3];
    }
    __builtin_nontemporal_store(a[0], (f32x4*)(out + (size_t)row * D + lofs));
}

// ===========================================================================
extern "C" void kernel_launch(void* const* d_in, const int* in_sizes, int n_in,
                              void* d_out, int out_size, void* d_ws, size_t ws_size,
                              hipStream_t stream) {
    const float* x        = (const float*)d_in[0];
    const float* edge_val = (const float*)d_in[1];
    const float* weight   = (const float*)d_in[2];
    const float* bias     = (const float*)d_in[3];
    const int*   edge_row = (const int*)d_in[4];
    const int*   edge_col = (const int*)d_in[5];
    float*       out      = (float*)d_out;

    const int N = in_sizes[0] / D;   // 100000
    const int E = in_sizes[1];       // 3200000

    char* ws = (char*)d_ws;
    size_t off = 0;
    auto carve = [&](size_t bytes) -> char* {
        char* p = ws + off;
        off = (off + bytes + 255) & ~(size_t)255;
        return p;
    };

    const int NB = (N + BROWS - 1) / BROWS;  // 782 buckets

    ushort* sup = (ushort*)carve((size_t)N * D * sizeof(ushort));   // 51.2 MB
    ushort* wt  = (ushort*)carve((size_t)D * D * sizeof(ushort));   // 128 KB
    unsigned long long* ebuck =
        (unsigned long long*)carve((size_t)E * sizeof(unsigned long long));  // 25.6 MB
    long long* epair = (long long*)carve((size_t)E * sizeof(long long));     // 25.6 MB
    int* row_start = (int*)carve((size_t)(N + 1) * sizeof(int));
    int* bcnt      = (int*)carve((size_t)NB * sizeof(int));
    int* bstart    = (int*)carve((size_t)(NB + 1) * sizeof(int));
    int* bcursor   = (int*)carve((size_t)NB * sizeof(int));

    const int nchunk = (E + CHUNK - 1) / CHUNK;  // 391

    // 1) W -> wt (bf16 transposed), support = bf16(x @ W)
    conv_wt<<<(D * D) / 256, 256, 0, stream>>>(weight, wt);
    gemm_mfma<<<(N + 63) / 64, 256, 0, stream>>>(x, wt, sup, N);

    // 2) bucket hist + scan
    zero_ints<<<(NB + 255) / 256, 256, 0, stream>>>(bcnt, NB);
    bucket_hist<<<nchunk, 256, 0, stream>>>(edge_row, bcnt, E, NB);
    bucket_scan<<<1, 512, 0, stream>>>(bcnt, bstart, bcursor, row_start, NB, N, E);

    // 3) two-level scatter: coarse buckets, then row-sorted epair (+row_start)
    bucket_scatter<<<nchunk, 256, 0, stream>>>(edge_row, edge_col, edge_val,
                                               bcursor, ebuck, E, NB);
    fine_scatter<<<NB, 256, 0, stream>>>(ebuck, bstart, epair, row_start, N);

    // 4) gather-accumulate (bias folded in)
    accumulate<<<(N + 3) / 4, 256, 0, stream>>>(sup, row_start, epair, bias, out, N);
}